// Round 1
// baseline (1144.831 us; speedup 1.0000x reference)
//
#include <hip/hip_runtime.h>
#include <math.h>

// EdgeNetEMD: BatchNorm(4) -> EdgeConv(8->32->32->2, relu_last) -> EdgeConv(4->32->32->4)
// N=100000 nodes, E=3200000 edges, fp32.

constexpr int DD  = 4;   // node feature dim
constexpr int BIG = 32;  // hidden dim
constexpr int HID = 2;   // encoder output dim

// ---------------- BatchNorm statistics ----------------
__global__ void bn_reduce_kernel(const float* __restrict__ x, int n,
                                 float* __restrict__ sums /* [8]: sum4, sumsq4 */)
{
    float s0=0.f,s1=0.f,s2=0.f,s3=0.f,q0=0.f,q1=0.f,q2=0.f,q3=0.f;
    int stride = gridDim.x * blockDim.x;
    for (int i = blockIdx.x * blockDim.x + threadIdx.x; i < n; i += stride) {
        float4 v = reinterpret_cast<const float4*>(x)[i];
        s0 += v.x; s1 += v.y; s2 += v.z; s3 += v.w;
        q0 = fmaf(v.x, v.x, q0); q1 = fmaf(v.y, v.y, q1);
        q2 = fmaf(v.z, v.z, q2); q3 = fmaf(v.w, v.w, q3);
    }
    #pragma unroll
    for (int off = 32; off >= 1; off >>= 1) {
        s0 += __shfl_down(s0, off); s1 += __shfl_down(s1, off);
        s2 += __shfl_down(s2, off); s3 += __shfl_down(s3, off);
        q0 += __shfl_down(q0, off); q1 += __shfl_down(q1, off);
        q2 += __shfl_down(q2, off); q3 += __shfl_down(q3, off);
    }
    __shared__ float red[4][8];
    int wave = threadIdx.x >> 6;
    int lane = threadIdx.x & 63;
    if (lane == 0) {
        red[wave][0]=s0; red[wave][1]=s1; red[wave][2]=s2; red[wave][3]=s3;
        red[wave][4]=q0; red[wave][5]=q1; red[wave][6]=q2; red[wave][7]=q3;
    }
    __syncthreads();
    if (threadIdx.x < 8) {
        int nw = blockDim.x >> 6;
        float t = 0.f;
        for (int w = 0; w < nw; ++w) t += red[w][threadIdx.x];
        atomicAdd(&sums[threadIdx.x], t);
    }
}

__global__ void bn_finalize_kernel(const float* __restrict__ sums,
                                   const float* __restrict__ gamma,
                                   const float* __restrict__ beta,
                                   float* __restrict__ ab, float invN)
{
    int f = threadIdx.x;
    if (f < DD) {
        float mean = sums[f] * invN;
        float var  = sums[DD + f] * invN - mean * mean;
        float a = gamma[f] / sqrtf(var + 1e-5f);
        ab[f]      = a;
        ab[DD + f] = beta[f] - mean * a;
    }
}

// ---------------- Encoder EdgeConv: in 8 -> 32 -> 32 -> 2 (relu) ----------------
__global__ __launch_bounds__(256) void enc_edge_kernel(
    const float* __restrict__ x, const int* __restrict__ src, const int* __restrict__ dst,
    const float* __restrict__ ab,
    const float* __restrict__ W1, const float* __restrict__ b1,
    const float* __restrict__ W2, const float* __restrict__ b2,
    const float* __restrict__ W3, const float* __restrict__ b3,
    float* __restrict__ acc, float* __restrict__ cnt, int E)
{
    int e = blockIdx.x * blockDim.x + threadIdx.x;
    if (e >= E) return;
    int si = src[e];
    int di = dst[e];
    float4 xd = reinterpret_cast<const float4*>(x)[di];
    float4 xs = reinterpret_cast<const float4*>(x)[si];
    float a0 = ab[0], a1 = ab[1], a2 = ab[2], a3 = ab[3];
    float c0 = ab[4], c1 = ab[5], c2 = ab[6], c3 = ab[7];

    float in[2 * DD];
    in[0] = fmaf(xd.x, a0, c0);
    in[1] = fmaf(xd.y, a1, c1);
    in[2] = fmaf(xd.z, a2, c2);
    in[3] = fmaf(xd.w, a3, c3);
    // (xj_norm - xi_norm) == (xj - xi) * a
    in[4] = (xs.x - xd.x) * a0;
    in[5] = (xs.y - xd.y) * a1;
    in[6] = (xs.z - xd.z) * a2;
    in[7] = (xs.w - xd.w) * a3;

    float h[BIG];
    #pragma unroll
    for (int j = 0; j < BIG; ++j) {
        float t = b1[j];
        #pragma unroll
        for (int k = 0; k < 2 * DD; ++k) t = fmaf(in[k], W1[k * BIG + j], t);
        h[j] = fmaxf(t, 0.0f);
    }
    float g[BIG];
    #pragma unroll
    for (int j = 0; j < BIG; ++j) {
        float t = b2[j];
        #pragma unroll
        for (int k = 0; k < BIG; ++k) t = fmaf(h[k], W2[k * BIG + j], t);
        g[j] = fmaxf(t, 0.0f);
    }
    float u0 = b3[0], u1 = b3[1];
    #pragma unroll
    for (int k = 0; k < BIG; ++k) {
        u0 = fmaf(g[k], W3[k * HID + 0], u0);
        u1 = fmaf(g[k], W3[k * HID + 1], u1);
    }
    u0 = fmaxf(u0, 0.0f);
    u1 = fmaxf(u1, 0.0f);

    atomicAdd(&acc[di * HID + 0], u0);
    atomicAdd(&acc[di * HID + 1], u1);
    atomicAdd(&cnt[di], 1.0f);
}

__global__ void finalize_h1_kernel(float* __restrict__ acc, const float* __restrict__ cnt, int n)
{
    int i = blockIdx.x * blockDim.x + threadIdx.x;
    if (i >= n) return;
    float inv = 1.0f / fmaxf(cnt[i], 1.0f);
    acc[i * HID + 0] *= inv;
    acc[i * HID + 1] *= inv;
}

// ---------------- Decoder EdgeConv: in 4 -> 32 -> 32 -> 4 (no relu) ----------------
__global__ __launch_bounds__(256) void dec_edge_kernel(
    const float* __restrict__ h1, const int* __restrict__ src, const int* __restrict__ dst,
    const float* __restrict__ W1, const float* __restrict__ b1,
    const float* __restrict__ W2, const float* __restrict__ b2,
    const float* __restrict__ W3, const float* __restrict__ b3,
    float* __restrict__ out, int E)
{
    int e = blockIdx.x * blockDim.x + threadIdx.x;
    if (e >= E) return;
    int si = src[e];
    int di = dst[e];
    float2 hd = reinterpret_cast<const float2*>(h1)[di];
    float2 hs = reinterpret_cast<const float2*>(h1)[si];

    float in[2 * HID];
    in[0] = hd.x;
    in[1] = hd.y;
    in[2] = hs.x - hd.x;
    in[3] = hs.y - hd.y;

    float h[BIG];
    #pragma unroll
    for (int j = 0; j < BIG; ++j) {
        float t = b1[j];
        #pragma unroll
        for (int k = 0; k < 2 * HID; ++k) t = fmaf(in[k], W1[k * BIG + j], t);
        h[j] = fmaxf(t, 0.0f);
    }
    float g[BIG];
    #pragma unroll
    for (int j = 0; j < BIG; ++j) {
        float t = b2[j];
        #pragma unroll
        for (int k = 0; k < BIG; ++k) t = fmaf(h[k], W2[k * BIG + j], t);
        g[j] = fmaxf(t, 0.0f);
    }
    float u0 = b3[0], u1 = b3[1], u2 = b3[2], u3 = b3[3];
    #pragma unroll
    for (int k = 0; k < BIG; ++k) {
        u0 = fmaf(g[k], W3[k * DD + 0], u0);
        u1 = fmaf(g[k], W3[k * DD + 1], u1);
        u2 = fmaf(g[k], W3[k * DD + 2], u2);
        u3 = fmaf(g[k], W3[k * DD + 3], u3);
    }

    atomicAdd(&out[di * DD + 0], u0);
    atomicAdd(&out[di * DD + 1], u1);
    atomicAdd(&out[di * DD + 2], u2);
    atomicAdd(&out[di * DD + 3], u3);
}

__global__ void finalize_out_kernel(float* __restrict__ out, const float* __restrict__ cnt, int n)
{
    int i = blockIdx.x * blockDim.x + threadIdx.x;
    if (i >= n) return;
    float inv = 1.0f / fmaxf(cnt[i], 1.0f);
    float4 v = reinterpret_cast<float4*>(out)[i];
    v.x *= inv; v.y *= inv; v.z *= inv; v.w *= inv;
    reinterpret_cast<float4*>(out)[i] = v;
}

// ---------------- launch ----------------
extern "C" void kernel_launch(void* const* d_in, const int* in_sizes, int n_in,
                              void* d_out, int out_size, void* d_ws, size_t ws_size,
                              hipStream_t stream)
{
    const float* x     = (const float*)d_in[0];
    const int*   src   = (const int*)  d_in[1];
    const int*   dst   = (const int*)  d_in[2];
    const float* gamma = (const float*)d_in[3];
    const float* beta  = (const float*)d_in[4];
    const float* eW1 = (const float*)d_in[5];  const float* eb1 = (const float*)d_in[6];
    const float* eW2 = (const float*)d_in[7];  const float* eb2 = (const float*)d_in[8];
    const float* eW3 = (const float*)d_in[9];  const float* eb3 = (const float*)d_in[10];
    const float* dW1 = (const float*)d_in[11]; const float* db1 = (const float*)d_in[12];
    const float* dW2 = (const float*)d_in[13]; const float* db2 = (const float*)d_in[14];
    const float* dW3 = (const float*)d_in[15]; const float* db3 = (const float*)d_in[16];

    const int N = in_sizes[0] / DD;
    const int E = in_sizes[1];

    float* ws   = (float*)d_ws;
    float* sums = ws;            // 8 floats
    float* ab   = ws + 8;        // 8 floats
    float* cnt  = ws + 16;       // N floats
    float* acc1 = ws + 16 + N;   // 2N floats
    float* out  = (float*)d_out; // 4N floats

    hipMemsetAsync(sums, 0, 16 * sizeof(float), stream);
    hipMemsetAsync(cnt, 0, (size_t)(3 * N) * sizeof(float), stream);  // cnt + acc1
    hipMemsetAsync(out, 0, (size_t)out_size * sizeof(float), stream);

    bn_reduce_kernel<<<256, 256, 0, stream>>>(x, N, sums);
    bn_finalize_kernel<<<1, 64, 0, stream>>>(sums, gamma, beta, ab, 1.0f / (float)N);

    int eblocks = (E + 255) / 256;
    enc_edge_kernel<<<eblocks, 256, 0, stream>>>(x, src, dst, ab,
                                                 eW1, eb1, eW2, eb2, eW3, eb3,
                                                 acc1, cnt, E);
    finalize_h1_kernel<<<(N + 255) / 256, 256, 0, stream>>>(acc1, cnt, N);

    dec_edge_kernel<<<eblocks, 256, 0, stream>>>(acc1, src, dst,
                                                 dW1, db1, dW2, db2, dW3, db3,
                                                 out, E);
    finalize_out_kernel<<<(N + 255) / 256, 256, 0, stream>>>(out, cnt, N);
}